// Round 4
// baseline (281.340 us; speedup 1.0000x reference)
//
#include <hip/hip_runtime.h>
#include <math.h>

typedef __attribute__((ext_vector_type(8))) _Float16 half8;
typedef __attribute__((ext_vector_type(4))) float    f32x4;

constexpr int D_DIM = 2048;
constexpr int NEXP  = 64;
constexpr int TOPK  = 8;
constexpr int NTOK  = 16384;        // B*S
constexpr int TM    = 64;           // tokens per WG
constexpr int OSTR  = 132;          // logit tile row stride (floats)
constexpr int NSTR  = 68;           // noise tile row stride (floats)
constexpr float WSCALE  = 4096.0f;  // W pre-scale (keeps fp16 lo out of subnormals)
constexpr float INV_WSC = 1.0f / 4096.0f;

__device__ __forceinline__ unsigned short f16b(float x) {
    _Float16 h = (_Float16)x;                       // v_cvt_f16_f32 (RNE)
    return __builtin_bit_cast(unsigned short, h);
}
__device__ __forceinline__ float f16tof(unsigned short b) {
    return (float)__builtin_bit_cast(_Float16, b);
}

// ---------------------------------------------------------------------------
// K1: split W*4096 (gate rows 0..63, noise rows 64..127) into fp16 hi/lo,
// packed B-fragment-linear: ws ushort layout
//   [chunk c (stride 8192)][ntile T (stride 1024)]{ hi 512 | lo 512 }
//   lane l holds B[k = c*32 + (l>>4)*8 + j][n = T*16 + (l&15)]
// ---------------------------------------------------------------------------
__global__ void prep_w(const float* __restrict__ Wg, const float* __restrict__ Wn,
                       unsigned short* __restrict__ wsB)
{
    const int idx = blockIdx.x * blockDim.x + threadIdx.x;   // 0..32767
    const int n   = idx >> 8;      // output row 0..127
    const int K8  = idx & 255;     // k-octet
    const float* src = (n < 64) ? (Wg + (size_t)n * D_DIM)
                                : (Wn + (size_t)(n - 64) * D_DIM);
    float4 a = *reinterpret_cast<const float4*>(src + K8 * 8);
    float4 b = *reinterpret_cast<const float4*>(src + K8 * 8 + 4);

    float v[8] = {a.x, a.y, a.z, a.w, b.x, b.y, b.z, b.w};
    union { unsigned short u[8]; half8 s; } H, L;
#pragma unroll
    for (int j = 0; j < 8; ++j) {
        float xs = v[j] * WSCALE;
        unsigned short h = f16b(xs);
        H.u[j] = h;
        L.u[j] = f16b(xs - f16tof(h));
    }
    const int l = ((K8 & 3) * 16) + (n & 15);
    const size_t base = (size_t)(K8 >> 2) * 8192 + (size_t)(n >> 4) * 1024 + (size_t)l * 8;
    *reinterpret_cast<half8*>(wsB + base)       = H.s;
    *reinterpret_cast<half8*>(wsB + base + 512) = L.s;
}

// ---------------------------------------------------------------------------
// K2: barrier-free K-loop. A loaded global->VGPR directly in fragment layout,
// fp16x2 split (3 MFMAs). Waves 0-3: chunks 0..31, waves 4-7: chunks 32..63;
// each wave: 2 n-tiles x 4 m-tiles. Partials combined through LDS in epilogue.
// ---------------------------------------------------------------------------
__global__ __launch_bounds__(512, 1)
void noisy_topk_router(const float* __restrict__ hs,
                       const unsigned short* __restrict__ wsB,
                       const float* __restrict__ nz,
                       float* __restrict__ out)
{
    __shared__ float logits[TM * OSTR];   // 33792 B
    __shared__ float ldsN[TM * NSTR];     // 17408 B

    const int tid  = threadIdx.x;
    const int lane = tid & 63;
    const int w    = tid >> 6;
    const int t0   = blockIdx.x * TM;
    const int kh   = w >> 2;              // K-half: 0 -> chunks 0..31, 1 -> 32..63
    const int wp   = w & 3;               // n-tile pair: ntiles 2wp, 2wp+1

    // A fragment address: lane l, mtile mt -> h[t0 + mt*16 + (l&15)][kh*1024 + (l>>4)*8 + c*32 + j]
    const float* abase = hs + (size_t)(t0 + (lane & 15)) * D_DIM + kh * 1024 + ((lane >> 4) * 8);
    // B fragment address (fragment-linear pack)
    const unsigned short* bbase = wsB + (size_t)(kh * 32) * 8192 + (size_t)(2 * wp) * 1024 + (size_t)lane * 8;

    f32x4 accH[4][2], accX[4][2];
#pragma unroll
    for (int mt = 0; mt < 4; ++mt)
#pragma unroll
        for (int ntk = 0; ntk < 2; ++ntk) {
            accH[mt][ntk] = (f32x4){0.f, 0.f, 0.f, 0.f};
            accX[mt][ntk] = (f32x4){0.f, 0.f, 0.f, 0.f};
        }

    // prologue: load chunk 0 raw
    float4 curA[4][2];
    uint4  curB[2][2];
#pragma unroll
    for (int mt = 0; mt < 4; ++mt) {
        const float* p = abase + (size_t)mt * (16 * D_DIM);
        curA[mt][0] = *reinterpret_cast<const float4*>(p);
        curA[mt][1] = *reinterpret_cast<const float4*>(p + 4);
    }
#pragma unroll
    for (int ntk = 0; ntk < 2; ++ntk) {
        const unsigned short* p = bbase + ntk * 1024;
        curB[ntk][0] = *reinterpret_cast<const uint4*>(p);
        curB[ntk][1] = *reinterpret_cast<const uint4*>(p + 512);
    }

#pragma unroll 2
    for (int c = 0; c < 32; ++c) {
        const int cn = (c + 1 < 32) ? (c + 1) : 31;   // clamped: last prefetch redundant, in-bounds

        // issue next chunk's loads (no barrier anywhere -> stays in flight across MFMAs)
        float4 nA[4][2];
        uint4  nB[2][2];
#pragma unroll
        for (int mt = 0; mt < 4; ++mt) {
            const float* p = abase + (size_t)mt * (16 * D_DIM) + cn * 32;
            nA[mt][0] = *reinterpret_cast<const float4*>(p);
            nA[mt][1] = *reinterpret_cast<const float4*>(p + 4);
        }
#pragma unroll
        for (int ntk = 0; ntk < 2; ++ntk) {
            const unsigned short* p = bbase + (size_t)cn * 8192 + ntk * 1024;
            nB[ntk][0] = *reinterpret_cast<const uint4*>(p);
            nB[ntk][1] = *reinterpret_cast<const uint4*>(p + 512);
        }

        // convert current A raw -> fp16 hi/lo fragments
        half8 ahi[4], alo[4];
#pragma unroll
        for (int mt = 0; mt < 4; ++mt) {
            float x[8] = {curA[mt][0].x, curA[mt][0].y, curA[mt][0].z, curA[mt][0].w,
                          curA[mt][1].x, curA[mt][1].y, curA[mt][1].z, curA[mt][1].w};
            union { unsigned short u[8]; half8 v; } H, L;
#pragma unroll
            for (int j = 0; j < 8; ++j) {
                unsigned short h = f16b(x[j]);
                H.u[j] = h;
                L.u[j] = f16b(x[j] - f16tof(h));
            }
            ahi[mt] = H.v;
            alo[mt] = L.v;
        }
        half8 bhi[2], blo[2];
#pragma unroll
        for (int ntk = 0; ntk < 2; ++ntk) {
            bhi[ntk] = __builtin_bit_cast(half8, curB[ntk][0]);
            blo[ntk] = __builtin_bit_cast(half8, curB[ntk][1]);
        }

#pragma unroll
        for (int mt = 0; mt < 4; ++mt)
#pragma unroll
            for (int ntk = 0; ntk < 2; ++ntk) {
                accH[mt][ntk] = __builtin_amdgcn_mfma_f32_16x16x32_f16(ahi[mt], bhi[ntk], accH[mt][ntk], 0, 0, 0);
                accX[mt][ntk] = __builtin_amdgcn_mfma_f32_16x16x32_f16(ahi[mt], blo[ntk], accX[mt][ntk], 0, 0, 0);
                accX[mt][ntk] = __builtin_amdgcn_mfma_f32_16x16x32_f16(alo[mt], bhi[ntk], accX[mt][ntk], 0, 0, 0);
            }

#pragma unroll
        for (int mt = 0; mt < 4; ++mt) { curA[mt][0] = nA[mt][0]; curA[mt][1] = nA[mt][1]; }
#pragma unroll
        for (int ntk = 0; ntk < 2; ++ntk) { curB[ntk][0] = nB[ntk][0]; curB[ntk][1] = nB[ntk][1]; }
    }

    // ---- combine K-halves through LDS logit tile ----
    // D layout: row = (lane>>4)*4 + reg, col = lane&15
    const int colb = 2 * wp * 16 + (lane & 15);
    const int rowb = (lane >> 4) * 4;
    if (w >= 4) {
#pragma unroll
        for (int mt = 0; mt < 4; ++mt)
#pragma unroll
            for (int ntk = 0; ntk < 2; ++ntk)
#pragma unroll
                for (int r = 0; r < 4; ++r)
                    logits[(mt * 16 + rowb + r) * OSTR + colb + ntk * 16] =
                        accH[mt][ntk][r] + accX[mt][ntk][r];
    }
    __syncthreads();
    if (w < 4) {
#pragma unroll
        for (int mt = 0; mt < 4; ++mt)
#pragma unroll
            for (int ntk = 0; ntk < 2; ++ntk)
#pragma unroll
                for (int r = 0; r < 4; ++r) {
                    const int idx = (mt * 16 + rowb + r) * OSTR + colb + ntk * 16;
                    logits[idx] = (logits[idx] + accH[mt][ntk][r] + accX[mt][ntk][r]) * INV_WSC;
                }
    }
    // stage noise tile coalesced (independent LDS region)
    {
        const int rr = tid >> 3;
        const int cc = tid & 7;
        const float* nrow = nz + (size_t)(t0 + rr) * NEXP;
#pragma unroll
        for (int p = 0; p < 2; ++p) {
            float4 v = *reinterpret_cast<const float4*>(nrow + cc * 4 + p * 32);
            *reinterpret_cast<float4*>(&ldsN[rr * NSTR + cc * 4 + p * 32]) = v;
        }
    }
    __syncthreads();

    if (tid < TM) {
        const int tok = t0 + tid;
        float l[NEXP];
        float mx = -3.0e38f;
#pragma unroll
        for (int e = 0; e < NEXP; ++e) {
            float gsc = logits[tid * OSTR + e];
            float nl  = logits[tid * OSTR + 64 + e];
            float sp  = fmaxf(nl, 0.0f) + log1pf(expf(-fabsf(nl)));   // softplus
            float le  = fmaf(ldsN[tid * NSTR + e], sp, gsc);
            l[e] = le;
            mx = fmaxf(mx, le);
        }
        float sum = 0.0f;
#pragma unroll
        for (int e = 0; e < NEXP; ++e) { float p = expf(l[e] - mx); l[e] = p; sum += p; }
        float inv = 1.0f / sum;
#pragma unroll
        for (int e = 0; e < NEXP; ++e) l[e] *= inv;

        // save gates for coalesced store
#pragma unroll
        for (int e = 0; e < NEXP; ++e) logits[tid * OSTR + e] = l[e];

        float* vout = out + (size_t)tok * TOPK;
        float* iout = out + (size_t)NTOK * TOPK + (size_t)tok * TOPK;
#pragma unroll
        for (int p = 0; p < TOPK; ++p) {
            float m = -1.0f; int mi = 0;
#pragma unroll
            for (int e = 0; e < NEXP; ++e) {
                bool gt = l[e] > m;        // strict > + ascending scan = lowest-index tie-break
                m  = gt ? l[e] : m;
                mi = gt ? e : mi;
            }
            vout[p] = m;
            iout[p] = (float)mi;
#pragma unroll
            for (int e = 0; e < NEXP; ++e) l[e] = (e == mi) ? -1.0f : l[e];
        }
    }
    __syncthreads();

    // coalesced gates store
    {
        const int rr = tid >> 3;
        const int cc = tid & 7;
        float* gout = out + (size_t)NTOK * TOPK * 2;
#pragma unroll
        for (int p = 0; p < 2; ++p) {
            float4 v = *reinterpret_cast<const float4*>(&logits[rr * OSTR + cc * 4 + p * 32]);
            *reinterpret_cast<float4*>(&gout[(size_t)(t0 + rr) * NEXP + cc * 4 + p * 32]) = v;
        }
    }
}

extern "C" void kernel_launch(void* const* d_in, const int* in_sizes, int n_in,
                              void* d_out, int out_size, void* d_ws, size_t ws_size,
                              hipStream_t stream) {
    const float* hs = (const float*)d_in[0];   // [4,4096,2048]
    const float* Wg = (const float*)d_in[1];   // [64,2048]
    const float* Wn = (const float*)d_in[2];   // [64,2048]
    const float* nz = (const float*)d_in[3];   // [4,4096,64]
    float* out = (float*)d_out;
    unsigned short* wsB = (unsigned short*)d_ws;   // 1 MB B-fragment pack (fp16 bits)

    prep_w<<<64, 512, 0, stream>>>(Wg, Wn, wsB);
    noisy_topk_router<<<NTOK / TM, 512, 0, stream>>>(hs, wsB, nz, out);
}

// Round 5
// 243.824 us; speedup vs baseline: 1.1539x; 1.1539x over previous
//
#include <hip/hip_runtime.h>
#include <math.h>

typedef __attribute__((ext_vector_type(8))) _Float16 half8;
typedef __attribute__((ext_vector_type(4))) float    f32x4;

constexpr int D_DIM = 2048;
constexpr int NEXP  = 64;
constexpr int TOPK  = 8;
constexpr int NTOK  = 16384;        // B*S
constexpr int TM    = 32;           // tokens per WG
constexpr int BK    = 64;           // K per staged chunk (2 MFMA ksteps)
constexpr int NCH   = D_DIM / BK;   // 32 chunks
constexpr int OSTR  = 132;          // logit tile row stride (floats)
constexpr int NSTR  = 68;           // noise tile row stride (floats)
constexpr float WSCALE  = 4096.0f;  // W pre-scale (keeps fp16 lo out of subnormals)
constexpr float INV_WSC = 1.0f / 4096.0f;

__device__ __forceinline__ unsigned short f16b(float x) {
    _Float16 h = (_Float16)x;                       // v_cvt_f16_f32 (RNE)
    return __builtin_bit_cast(unsigned short, h);
}
__device__ __forceinline__ float f16tof(unsigned short b) {
    return (float)__builtin_bit_cast(_Float16, b);
}

// ---------------------------------------------------------------------------
// K1: split W*4096 (gate rows 0..63, noise rows 64..127) into fp16 hi/lo,
// packed B-fragment-linear: ws ushort layout
//   [chunk32 c (stride 8192)][ntile T (stride 1024)]{ hi 512 | lo 512 }
//   lane l holds B[k = c*32 + (l>>4)*8 + j][n = T*16 + (l&15)]
// ---------------------------------------------------------------------------
__global__ void prep_w(const float* __restrict__ Wg, const float* __restrict__ Wn,
                       unsigned short* __restrict__ wsB)
{
    const int idx = blockIdx.x * blockDim.x + threadIdx.x;   // 0..32767
    const int n   = idx >> 8;      // output row 0..127
    const int K8  = idx & 255;     // k-octet
    const float* src = (n < 64) ? (Wg + (size_t)n * D_DIM)
                                : (Wn + (size_t)(n - 64) * D_DIM);
    float4 a = *reinterpret_cast<const float4*>(src + K8 * 8);
    float4 b = *reinterpret_cast<const float4*>(src + K8 * 8 + 4);

    float v[8] = {a.x, a.y, a.z, a.w, b.x, b.y, b.z, b.w};
    union { unsigned short u[8]; half8 s; } H, L;
#pragma unroll
    for (int j = 0; j < 8; ++j) {
        float xs = v[j] * WSCALE;
        unsigned short h = f16b(xs);
        H.u[j] = h;
        L.u[j] = f16b(xs - f16tof(h));
    }
    const int l = ((K8 & 3) * 16) + (n & 15);
    const size_t base = (size_t)(K8 >> 2) * 8192 + (size_t)(n >> 4) * 1024 + (size_t)l * 8;
    *reinterpret_cast<half8*>(wsB + base)       = H.s;
    *reinterpret_cast<half8*>(wsB + base + 512) = L.s;
}

// ---------------------------------------------------------------------------
// K2: TM=32 tokens/WG, grid 512 (2 WGs/CU). Coalesced global->reg->cvt->LDS
// staging in fragment-linear fp16 hi/lo, BK=64 (1 barrier / 2 MFMA ksteps),
// prefetch issued right after the barrier. Wave w = n-tile w, 2 m-tiles, full K.
// ---------------------------------------------------------------------------
__global__ __launch_bounds__(512, 4)
void noisy_topk_router(const float* __restrict__ hs,
                       const unsigned short* __restrict__ wsB,
                       const float* __restrict__ nz,
                       float* __restrict__ out)
{
    // stage: 2 bufs x 4096 ushorts (8 KB: hi 2048 | lo 2048), total 16 KB
    // epilogue union: logits 32x132 f32 (16896 B) + noise 32x68 f32 (8704 B)
    __shared__ __align__(16) char smem[16896 + 8704];
    unsigned short* stage  = reinterpret_cast<unsigned short*>(smem);
    float*          logits = reinterpret_cast<float*>(smem);
    float*          ldsN   = reinterpret_cast<float*>(smem + 16896);

    const int tid  = threadIdx.x;
    const int lane = tid & 63;
    const int w    = tid >> 6;          // wave id = n-tile (outputs w*16..+16)
    const int t0   = blockIdx.x * TM;

    // staging role: thread t -> row r = t>>4 (0..31), k4 = (t&15)*4 within chunk
    const int r  = tid >> 4;
    const int k4 = (tid & 15) * 4;
    const float* hrow = hs + (size_t)(t0 + r) * D_DIM + k4;
    // fragment-linear write offset (ushort units, within one ver region):
    //   [mt*2+ks]*512 + (j0*16 + m)*8 + pos
    const int ks_s = k4 >> 5;
    const int kk   = k4 & 31;
    const int j0   = kk >> 3;
    const int pos  = kk & 7;            // 0 or 4
    const int mt_s = r >> 4;
    const int m_s  = r & 15;
    const int wroff = (mt_s * 2 + ks_s) * 512 + (j0 * 16 + m_s) * 8 + pos;

    f32x4 accH0[2], accH1[2], accX[2];
#pragma unroll
    for (int mt = 0; mt < 2; ++mt) {
        accH0[mt] = (f32x4){0.f, 0.f, 0.f, 0.f};
        accH1[mt] = (f32x4){0.f, 0.f, 0.f, 0.f};
        accX[mt]  = (f32x4){0.f, 0.f, 0.f, 0.f};
    }

    auto cvt_write = [&](float4 v, unsigned short* buf) {
        float p[4] = {v.x, v.y, v.z, v.w};
        unsigned int Hp[2], Lp[2];
#pragma unroll
        for (int q = 0; q < 2; ++q) {
            unsigned short h0 = f16b(p[2*q]);
            unsigned short h1 = f16b(p[2*q+1]);
            unsigned short l0 = f16b(p[2*q]   - f16tof(h0));
            unsigned short l1 = f16b(p[2*q+1] - f16tof(h1));
            Hp[q] = (unsigned int)h0 | ((unsigned int)h1 << 16);
            Lp[q] = (unsigned int)l0 | ((unsigned int)l1 << 16);
        }
        *reinterpret_cast<uint2*>(buf + wroff)        = make_uint2(Hp[0], Hp[1]);
        *reinterpret_cast<uint2*>(buf + 2048 + wroff) = make_uint2(Lp[0], Lp[1]);
    };

    // prologue: stage chunk 0 (load fully waited before barrier -> no drain cost)
    cvt_write(*reinterpret_cast<const float4*>(hrow), stage);
    __syncthreads();

    for (int c = 0; c < NCH; ++c) {
        // prefetch for c+1 issued FIRST in the region (max latency budget;
        // consumed at region end, so the end barrier drains only the residual)
        float4 pf;
        if (c + 1 < NCH)
            pf = *reinterpret_cast<const float4*>(hrow + (c + 1) * BK);

        const unsigned short* sb = stage + (c & 1) * 4096;

#pragma unroll
        for (int ks = 0; ks < 2; ++ks) {
            const unsigned short* bp = wsB + (size_t)(2 * c + ks) * 8192
                                           + (size_t)w * 1024 + (size_t)lane * 8;
            half8 bhi = *reinterpret_cast<const half8*>(bp);
            half8 blo = *reinterpret_cast<const half8*>(bp + 512);
#pragma unroll
            for (int mt = 0; mt < 2; ++mt) {
                half8 ahi = *reinterpret_cast<const half8*>(sb + (mt * 2 + ks) * 512 + lane * 8);
                half8 alo = *reinterpret_cast<const half8*>(sb + 2048 + (mt * 2 + ks) * 512 + lane * 8);
                if (ks == 0)
                    accH0[mt] = __builtin_amdgcn_mfma_f32_16x16x32_f16(ahi, bhi, accH0[mt], 0, 0, 0);
                else
                    accH1[mt] = __builtin_amdgcn_mfma_f32_16x16x32_f16(ahi, bhi, accH1[mt], 0, 0, 0);
                accX[mt] = __builtin_amdgcn_mfma_f32_16x16x32_f16(ahi, blo, accX[mt], 0, 0, 0);
                accX[mt] = __builtin_amdgcn_mfma_f32_16x16x32_f16(alo, bhi, accX[mt], 0, 0, 0);
            }
        }

        if (c + 1 < NCH)
            cvt_write(pf, stage + ((c + 1) & 1) * 4096);
        __syncthreads();   // one barrier per chunk64: buf swap + write visibility
    }

    // ---- epilogue: wave-local results -> logit tile (stage region is dead now) ----
    {
        const int colb = w * 16 + (lane & 15);
        const int rowb = (lane >> 4) * 4;
#pragma unroll
        for (int mt = 0; mt < 2; ++mt)
#pragma unroll
            for (int rr = 0; rr < 4; ++rr)
                logits[(mt * 16 + rowb + rr) * OSTR + colb] =
                    (accH0[mt][rr] + accH1[mt][rr] + accX[mt][rr]) * INV_WSC;
    }
    // stage noise tile coalesced: 512 threads x 1 float4 = 32 rows x 64 floats
    {
        const int rr = tid >> 4;
        const int cc = tid & 15;
        float4 v = *reinterpret_cast<const float4*>(nz + (size_t)(t0 + rr) * NEXP + cc * 4);
        *reinterpret_cast<float4*>(&ldsN[rr * NSTR + cc * 4]) = v;
    }
    __syncthreads();

    if (tid < TM) {
        const int tok = t0 + tid;
        float l[NEXP];
        float mx = -3.0e38f;
#pragma unroll
        for (int e = 0; e < NEXP; ++e) {
            float gsc = logits[tid * OSTR + e];
            float nl  = logits[tid * OSTR + 64 + e];
            float sp  = fmaxf(nl, 0.0f) + log1pf(expf(-fabsf(nl)));   // softplus
            float le  = fmaf(ldsN[tid * NSTR + e], sp, gsc);
            l[e] = le;
            mx = fmaxf(mx, le);
        }
        float sum = 0.0f;
#pragma unroll
        for (int e = 0; e < NEXP; ++e) { float p = expf(l[e] - mx); l[e] = p; sum += p; }
        float inv = 1.0f / sum;
#pragma unroll
        for (int e = 0; e < NEXP; ++e) l[e] *= inv;

        // save gates for coalesced store
#pragma unroll
        for (int e = 0; e < NEXP; ++e) logits[tid * OSTR + e] = l[e];

        float* vout = out + (size_t)tok * TOPK;
        float* iout = out + (size_t)NTOK * TOPK + (size_t)tok * TOPK;
#pragma unroll
        for (int p = 0; p < TOPK; ++p) {
            float m = -1.0f; int mi = 0;
#pragma unroll
            for (int e = 0; e < NEXP; ++e) {
                bool gt = l[e] > m;        // strict > + ascending scan = lowest-index tie-break
                m  = gt ? l[e] : m;
                mi = gt ? e : mi;
            }
            vout[p] = m;
            iout[p] = (float)mi;
#pragma unroll
            for (int e = 0; e < NEXP; ++e) l[e] = (e == mi) ? -1.0f : l[e];
        }
    }
    __syncthreads();

    // coalesced gates store: 512 threads x 1 float4
    {
        const int rr = tid >> 4;
        const int cc = tid & 15;
        float* gout = out + (size_t)NTOK * TOPK * 2;
        float4 v = *reinterpret_cast<const float4*>(&logits[rr * OSTR + cc * 4]);
        *reinterpret_cast<float4*>(&gout[(size_t)(t0 + rr) * NEXP + cc * 4]) = v;
    }
}

extern "C" void kernel_launch(void* const* d_in, const int* in_sizes, int n_in,
                              void* d_out, int out_size, void* d_ws, size_t ws_size,
                              hipStream_t stream) {
    const float* hs = (const float*)d_in[0];   // [4,4096,2048]
    const float* Wg = (const float*)d_in[1];   // [64,2048]
    const float* Wn = (const float*)d_in[2];   // [64,2048]
    const float* nz = (const float*)d_in[3];   // [4,4096,64]
    float* out = (float*)d_out;
    unsigned short* wsB = (unsigned short*)d_ws;   // 1 MB B-fragment pack (fp16 bits)

    prep_w<<<64, 512, 0, stream>>>(Wg, Wn, wsB);
    noisy_topk_router<<<NTOK / TM, 512, 0, stream>>>(hs, wsB, nz, out);
}